// Round 1
// baseline (363.202 us; speedup 1.0000x reference)
//
#include <hip/hip_runtime.h>

typedef __attribute__((ext_vector_type(8))) short s16x8;
typedef __attribute__((ext_vector_type(4))) float f32x4;

#define CHN 512
#define NSP 4096

__device__ __forceinline__ ushort f2b(float f){
  unsigned u = __builtin_bit_cast(unsigned, f);
  u = (u + 0x7fffu + ((u >> 16) & 1u)) >> 16;
  return (ushort)u;
}

__device__ __forceinline__ s16x8 ldfrag(const void* p){
  return *reinterpret_cast<const s16x8*>(p);
}

__device__ __forceinline__ f32x4 mfma16(s16x8 a, s16x8 b, f32x4 c){
  return __builtin_amdgcn_mfma_f32_16x16x32_bf16(a, b, c, 0, 0, 0);
}

// ---------- group-norm statistics: 32 groups, each 16ch x 4096 = 64K contiguous floats ----------
__global__ __launch_bounds__(256) void gn_stats(const float* __restrict__ x, float* __restrict__ stat){
  int g = blockIdx.x;
  const float4* p = reinterpret_cast<const float4*>(x + (size_t)g * 65536);
  float s = 0.f, s2 = 0.f;
  for (int i = threadIdx.x; i < 16384; i += 256){
    float4 v = p[i];
    s  += v.x + v.y + v.z + v.w;
    s2 += v.x*v.x + v.y*v.y + v.z*v.z + v.w*v.w;
  }
  #pragma unroll
  for (int off = 32; off > 0; off >>= 1){ s += __shfl_down(s, off); s2 += __shfl_down(s2, off); }
  __shared__ float ls[4], ls2[4];
  int wv = threadIdx.x >> 6;
  if ((threadIdx.x & 63) == 0){ ls[wv] = s; ls2[wv] = s2; }
  __syncthreads();
  if (threadIdx.x == 0){
    s  = ls[0]+ls[1]+ls[2]+ls[3];
    s2 = ls2[0]+ls2[1]+ls2[2]+ls2[3];
    float mu  = s * (1.f/65536.f);
    float var = s2 * (1.f/65536.f) - mu*mu;
    stat[g]      = mu;
    stat[32 + g] = rsqrtf(var + 1e-5f);
  }
}

// ---------- fused norm + SiLU + transpose: x (C,N) fp32 -> h_t (N,C) bf16 ----------
__global__ __launch_bounds__(256) void norm_apply(const float* __restrict__ x, const float* __restrict__ stat,
                                                  const float* __restrict__ nw, const float* __restrict__ nb,
                                                  ushort* __restrict__ h_t){
  __shared__ float tile[64][65];
  int ct0 = (blockIdx.x >> 6) << 6;   // 8 c-tiles
  int nt0 = (blockIdx.x & 63) << 6;   // 64 n-tiles
  int tc = threadIdx.x >> 6;          // 0..3
  int tn = threadIdx.x & 63;
  #pragma unroll
  for (int rr = 0; rr < 16; ++rr){
    int cl = rr*4 + tc;
    int c  = ct0 + cl;
    float v  = x[(size_t)c * NSP + nt0 + tn];
    float hn = (v - stat[c >> 4]) * stat[32 + (c >> 4)] * nw[c] + nb[c];
    float sv = hn / (1.f + __expf(-hn));
    tile[tn][cl] = sv;
  }
  __syncthreads();
  #pragma unroll
  for (int rr = 0; rr < 16; ++rr){
    int nl = rr*4 + tc;
    h_t[(size_t)(nt0 + nl) * CHN + ct0 + tn] = f2b(tile[nl][tn]);
  }
}

// ---------- fp32 -> bf16 weight conversion ----------
__global__ __launch_bounds__(256) void cvt_bf16(const float4* __restrict__ in, ushort4* __restrict__ out, int n4){
  int i = blockIdx.x * 256 + threadIdx.x;
  if (i < n4){
    float4 v = in[i];
    ushort4 o;
    o.x = f2b(v.x); o.y = f2b(v.y); o.z = f2b(v.z); o.w = f2b(v.w);
    out[i] = o;
  }
}

// ---------- GEMM: C(n,o) = A(n,c) * Bw(o,c)^T, 128x128 tile, 4 waves, 4x4 frags/wave ----------
// MODE 0: qkv epilogue -> scatter into qS/kS/vS per the torch reshape semantics
//         head h = n/512, a = n%512, b = co/64, d' = co%64 ; seq index n' = 8a+b
//         qS/kS: [(h*8+b)*512 + a][d']   vS: [(h*8+b)*64 + d'][a]
// MODE 1: proj epilogue -> out = x + bias + acc (fp32)
template<int MODE>
__global__ __launch_bounds__(256) void gemm_tn(
    const ushort* __restrict__ A, const ushort* __restrict__ Bw,
    const float* __restrict__ bias, const float* __restrict__ xres,
    ushort* __restrict__ qS, ushort* __restrict__ kS, ushort* __restrict__ vS,
    float* __restrict__ outF)
{
  int lane = threadIdx.x & 63, wv = threadIdx.x >> 6;
  int lr = lane & 15, lg = lane >> 4;
  int nb = blockIdx.x * 128 + (wv >> 1) * 64;
  int ob = blockIdx.y * 128 + (wv & 1) * 64;
  f32x4 acc[4][4] = {};
  const ushort* Ap = A  + (size_t)(nb + lr) * CHN + lg * 8;
  const ushort* Bp = Bw + (size_t)(ob + lr) * CHN + lg * 8;
  for (int kk = 0; kk < CHN; kk += 32){
    s16x8 af[4], bf[4];
    #pragma unroll
    for (int t = 0; t < 4; ++t) af[t] = ldfrag(Ap + (size_t)t*16*CHN + kk);
    #pragma unroll
    for (int t = 0; t < 4; ++t) bf[t] = ldfrag(Bp + (size_t)t*16*CHN + kk);
    #pragma unroll
    for (int i = 0; i < 4; ++i)
      #pragma unroll
      for (int j = 0; j < 4; ++j)
        acc[i][j] = mfma16(af[i], bf[j], acc[i][j]);
  }
  if (MODE == 0){
    #pragma unroll
    for (int j = 0; j < 4; ++j){
      int o = ob + j*16 + lr;
      float bs = bias[o];
      int sec = o >> 9;        // 0=Q 1=K 2=V (uniform per wave: ob multiple of 64)
      int co  = o & 511;
      int bb = co >> 6, dd = co & 63;
      #pragma unroll
      for (int i = 0; i < 4; ++i){
        int n0 = nb + i*16 + lg*4;
        int hh = n0 >> 9, aa = n0 & 511;
        if (sec == 2){
          ushort4 pk;
          pk.x = f2b(acc[i][j][0] + bs);
          pk.y = f2b(acc[i][j][1] + bs);
          pk.z = f2b(acc[i][j][2] + bs);
          pk.w = f2b(acc[i][j][3] + bs);
          *reinterpret_cast<ushort4*>(vS + ((size_t)((hh<<3)+bb)*64 + dd)*512 + aa) = pk;
        } else {
          ushort* dst = (sec == 0) ? qS : kS;
          size_t base = ((size_t)((hh<<3)+bb)*512 + aa)*64 + dd;
          #pragma unroll
          for (int r = 0; r < 4; ++r)
            dst[base + (size_t)r*64] = f2b(acc[i][j][r] + bs);
        }
      }
    }
  } else {
    #pragma unroll
    for (int j = 0; j < 4; ++j){
      int o = ob + j*16 + lr;
      float bs = bias[o];
      #pragma unroll
      for (int i = 0; i < 4; ++i){
        int n0 = nb + i*16 + lg*4;
        f32x4 xr = *reinterpret_cast<const f32x4*>(xres + (size_t)o*NSP + n0);
        f32x4 ov;
        #pragma unroll
        for (int r = 0; r < 4; ++r) ov[r] = acc[i][j][r] + bs + xr[r];
        *reinterpret_cast<f32x4*>(outF + (size_t)o*NSP + n0) = ov;
      }
    }
  }
}

// ---------- flash attention: block = (head h, q channel-block b1, 64 q-rows a) ----------
// online softmax in exp2 domain; P routed C-layout -> A-layout via padded per-wave LDS
__global__ __launch_bounds__(256) void flash(
    const ushort* __restrict__ qS, const ushort* __restrict__ kS,
    const ushort* __restrict__ vS, ushort* __restrict__ attnT)
{
  __shared__ __align__(16) ushort Pl[4][16][72];
  int lane = threadIdx.x & 63, wv = threadIdx.x >> 6;
  int lr = lane & 15, lg = lane >> 4;
  int hh = blockIdx.x >> 6;
  int b1 = (blockIdx.x >> 3) & 7;
  int a0 = (blockIdx.x & 7) * 64;
  const ushort* qp = qS + ((size_t)((hh*8 + b1)*512) + a0 + wv*16 + lr)*64 + lg*8;
  s16x8 aq0 = ldfrag(qp), aq1 = ldfrag(qp + 32);
  f32x4 O[4] = {};
  float mrun[4] = {-1e30f, -1e30f, -1e30f, -1e30f};
  float lrun[4] = {0.f, 0.f, 0.f, 0.f};
  const float sc = 0.125f * 1.4426950408889634f;   // scale * log2(e)
  for (int b2 = 0; b2 < 8; ++b2){
    const ushort* kb = kS + ((size_t)((hh*8 + b2)*512) + lr)*64  + lg*8;
    const ushort* vb = vS + ((size_t)((hh*8 + b2)*64)  + lr)*512 + lg*8;
    for (int a2 = 0; a2 < 512; a2 += 64){
      f32x4 S[4];
      #pragma unroll
      for (int mt = 0; mt < 4; ++mt){
        const ushort* kp = kb + (size_t)(a2 + mt*16)*64;
        f32x4 z = {0.f, 0.f, 0.f, 0.f};
        z = mfma16(aq0, ldfrag(kp), z);
        z = mfma16(aq1, ldfrag(kp + 32), z);
        S[mt] = z;
      }
      #pragma unroll
      for (int r = 0; r < 4; ++r){
        float s0 = S[0][r]*sc, s1 = S[1][r]*sc, s2 = S[2][r]*sc, s3 = S[3][r]*sc;
        float mx = fmaxf(fmaxf(s0, s1), fmaxf(s2, s3));
        #pragma unroll
        for (int d = 1; d < 16; d <<= 1) mx = fmaxf(mx, __shfl_xor(mx, d));
        float mnew  = fmaxf(mrun[r], mx);
        float alpha = exp2f(mrun[r] - mnew);
        s0 = exp2f(s0 - mnew); s1 = exp2f(s1 - mnew);
        s2 = exp2f(s2 - mnew); s3 = exp2f(s3 - mnew);
        float rs_ = s0 + s1 + s2 + s3;
        #pragma unroll
        for (int d = 1; d < 16; d <<= 1) rs_ += __shfl_xor(rs_, d);
        lrun[r] = lrun[r]*alpha + rs_;
        mrun[r] = mnew;
        S[0][r] = s0; S[1][r] = s1; S[2][r] = s2; S[3][r] = s3;
        #pragma unroll
        for (int dt = 0; dt < 4; ++dt) O[dt][r] *= alpha;
      }
      #pragma unroll
      for (int mt = 0; mt < 4; ++mt)
        #pragma unroll
        for (int r = 0; r < 4; ++r)
          Pl[wv][lg*4 + r][mt*16 + lr] = f2b(S[mt][r]);
      asm volatile("s_waitcnt lgkmcnt(0)" ::: "memory");
      const ushort* pp = &Pl[wv][lr][lg*8];
      s16x8 pa0 = ldfrag(pp), pa1 = ldfrag(pp + 32);
      #pragma unroll
      for (int dt = 0; dt < 4; ++dt){
        const ushort* vp = vb + (size_t)dt*16*512 + a2;
        O[dt] = mfma16(pa0, ldfrag(vp), O[dt]);
        O[dt] = mfma16(pa1, ldfrag(vp + 32), O[dt]);
      }
    }
  }
  float inv[4];
  #pragma unroll
  for (int r = 0; r < 4; ++r) inv[r] = 1.f / lrun[r];
  size_t nrow = (size_t)hh*512 + a0 + wv*16 + lg*4;
  #pragma unroll
  for (int dt = 0; dt < 4; ++dt)
    #pragma unroll
    for (int r = 0; r < 4; ++r)
      attnT[(nrow + r)*CHN + b1*64 + dt*16 + lr] = f2b(O[dt][r]*inv[r]);
}

extern "C" void kernel_launch(void* const* d_in, const int* in_sizes, int n_in,
                              void* d_out, int out_size, void* d_ws, size_t ws_size,
                              hipStream_t stream)
{
  (void)in_sizes; (void)n_in; (void)out_size; (void)ws_size;
  const float* x     = (const float*)d_in[0];
  const float* normw = (const float*)d_in[1];
  const float* normb = (const float*)d_in[2];
  const float* qkvw  = (const float*)d_in[3];
  const float* qkvb  = (const float*)d_in[4];
  const float* projw = (const float*)d_in[5];
  const float* projb = (const float*)d_in[6];
  float* out = (float*)d_out;

  char* w = (char*)d_ws;
  float*  stat = (float*)w;                                        // 1 KB
  ushort* h_t  = (ushort*)(w + 1024);                              // 4 MB (n,c) bf16 ; aliased as attnT
  ushort* Wq   = (ushort*)(w + 1024 + 4194304);                    // 1.5 MB
  ushort* Wp   = (ushort*)(w + 1024 + 4194304 + 1572864);          // 0.5 MB
  ushort* qSb  = (ushort*)(w + 1024 + 4194304 + 1572864 + 524288); // 4 MB
  ushort* kSb  = qSb + 2097152;                                    // 4 MB
  ushort* vSb  = kSb + 2097152;                                    // 4 MB
  ushort* attnT = h_t;

  cvt_bf16<<<768, 256, 0, stream>>>((const float4*)qkvw, (ushort4*)Wq, 196608);
  cvt_bf16<<<256, 256, 0, stream>>>((const float4*)projw, (ushort4*)Wp, 65536);
  gn_stats<<<32, 256, 0, stream>>>(x, stat);
  norm_apply<<<512, 256, 0, stream>>>(x, stat, normw, normb, h_t);
  gemm_tn<0><<<dim3(32, 12), 256, 0, stream>>>(h_t, Wq, qkvb, nullptr, qSb, kSb, vSb, nullptr);
  flash<<<512, 256, 0, stream>>>(qSb, kSb, vSb, attnT);
  gemm_tn<1><<<dim3(32, 4), 256, 0, stream>>>(attnT, Wp, projb, x, nullptr, nullptr, nullptr, out);
}

// Round 2
// 209.066 us; speedup vs baseline: 1.7373x; 1.7373x over previous
//
#include <hip/hip_runtime.h>

typedef __attribute__((ext_vector_type(8)))  short s16x8;
typedef __attribute__((ext_vector_type(4)))  float f32x4;
typedef __attribute__((ext_vector_type(16))) float f32x16;
typedef __attribute__((ext_vector_type(4)))  unsigned int u32x4;

#define CHN 512
#define NSP 4096

__device__ __forceinline__ ushort f2b(float f){
  unsigned u = __builtin_bit_cast(unsigned, f);
  u = (u + 0x7fffu + ((u >> 16) & 1u)) >> 16;
  return (ushort)u;
}

__device__ __forceinline__ s16x8 ldfrag(const void* p){
  return *reinterpret_cast<const s16x8*>(p);
}

__device__ __forceinline__ f32x4 mfma16(s16x8 a, s16x8 b, f32x4 c){
  return __builtin_amdgcn_mfma_f32_16x16x32_bf16(a, b, c, 0, 0, 0);
}
__device__ __forceinline__ f32x16 mfma32(s16x8 a, s16x8 b, f32x16 c){
  return __builtin_amdgcn_mfma_f32_32x32x16_bf16(a, b, c, 0, 0, 0);
}
__device__ __forceinline__ unsigned cvtpk(float lo, float hi){
  unsigned r;
  asm("v_cvt_pk_bf16_f32 %0, %1, %2" : "=v"(r) : "v"(lo), "v"(hi));
  return r;
}

// ---------- group-norm statistics ----------
__global__ __launch_bounds__(256) void gn_stats(const float* __restrict__ x, float* __restrict__ stat){
  int g = blockIdx.x;
  const float4* p = reinterpret_cast<const float4*>(x + (size_t)g * 65536);
  float s = 0.f, s2 = 0.f;
  for (int i = threadIdx.x; i < 16384; i += 256){
    float4 v = p[i];
    s  += v.x + v.y + v.z + v.w;
    s2 += v.x*v.x + v.y*v.y + v.z*v.z + v.w*v.w;
  }
  #pragma unroll
  for (int off = 32; off > 0; off >>= 1){ s += __shfl_down(s, off); s2 += __shfl_down(s2, off); }
  __shared__ float ls[4], ls2[4];
  int wv = threadIdx.x >> 6;
  if ((threadIdx.x & 63) == 0){ ls[wv] = s; ls2[wv] = s2; }
  __syncthreads();
  if (threadIdx.x == 0){
    s  = ls[0]+ls[1]+ls[2]+ls[3];
    s2 = ls2[0]+ls2[1]+ls2[2]+ls2[3];
    float mu  = s * (1.f/65536.f);
    float var = s2 * (1.f/65536.f) - mu*mu;
    stat[g]      = mu;
    stat[32 + g] = rsqrtf(var + 1e-5f);
  }
}

// ---------- fused norm + SiLU + transpose: x (C,N) fp32 -> h_t (N,C) bf16 ----------
__global__ __launch_bounds__(256) void norm_apply(const float* __restrict__ x, const float* __restrict__ stat,
                                                  const float* __restrict__ nw, const float* __restrict__ nb,
                                                  ushort* __restrict__ h_t){
  __shared__ float tile[64][65];
  int ct0 = (blockIdx.x >> 6) << 6;
  int nt0 = (blockIdx.x & 63) << 6;
  int tc = threadIdx.x >> 6;
  int tn = threadIdx.x & 63;
  #pragma unroll
  for (int rr = 0; rr < 16; ++rr){
    int cl = rr*4 + tc;
    int c  = ct0 + cl;
    float v  = x[(size_t)c * NSP + nt0 + tn];
    float hn = (v - stat[c >> 4]) * stat[32 + (c >> 4)] * nw[c] + nb[c];
    float sv = hn / (1.f + __expf(-hn));
    tile[tn][cl] = sv;
  }
  __syncthreads();
  #pragma unroll
  for (int rr = 0; rr < 16; ++rr){
    int nl = rr*4 + tc;
    h_t[(size_t)(nt0 + nl) * CHN + ct0 + tn] = f2b(tile[nl][tn]);
  }
}

// ---------- fp32 -> bf16 weight conversion ----------
__global__ __launch_bounds__(256) void cvt_bf16(const float4* __restrict__ in, ushort4* __restrict__ out, int n4){
  int i = blockIdx.x * 256 + threadIdx.x;
  if (i < n4){
    float4 v = in[i];
    ushort4 o;
    o.x = f2b(v.x); o.y = f2b(v.y); o.z = f2b(v.z); o.w = f2b(v.w);
    out[i] = o;
  }
}

// ---------- GEMM: C(n,o) = A(n,c) * Bw(o,c)^T ----------
// MODE 0: qkv epilogue -> scatter into qS/kS/vS ; Q pre-scaled by 0.125*log2(e)
// MODE 1: proj epilogue -> out = x + bias + acc (fp32)
template<int MODE>
__global__ __launch_bounds__(256) void gemm_tn(
    const ushort* __restrict__ A, const ushort* __restrict__ Bw,
    const float* __restrict__ bias, const float* __restrict__ xres,
    ushort* __restrict__ qS, ushort* __restrict__ kS, ushort* __restrict__ vS,
    float* __restrict__ outF)
{
  int lane = threadIdx.x & 63, wv = threadIdx.x >> 6;
  int lr = lane & 15, lg = lane >> 4;
  int nb = blockIdx.x * 128 + (wv >> 1) * 64;
  int ob = blockIdx.y * 128 + (wv & 1) * 64;
  f32x4 acc[4][4] = {};
  const ushort* Ap = A  + (size_t)(nb + lr) * CHN + lg * 8;
  const ushort* Bp = Bw + (size_t)(ob + lr) * CHN + lg * 8;
  for (int kk = 0; kk < CHN; kk += 32){
    s16x8 af[4], bf[4];
    #pragma unroll
    for (int t = 0; t < 4; ++t) af[t] = ldfrag(Ap + (size_t)t*16*CHN + kk);
    #pragma unroll
    for (int t = 0; t < 4; ++t) bf[t] = ldfrag(Bp + (size_t)t*16*CHN + kk);
    #pragma unroll
    for (int i = 0; i < 4; ++i)
      #pragma unroll
      for (int j = 0; j < 4; ++j)
        acc[i][j] = mfma16(af[i], bf[j], acc[i][j]);
  }
  if (MODE == 0){
    #pragma unroll
    for (int j = 0; j < 4; ++j){
      int o = ob + j*16 + lr;
      float bs = bias[o];
      int sec = o >> 9;        // 0=Q 1=K 2=V
      int co  = o & 511;
      int bb = co >> 6, dd = co & 63;
      float qsc = (sec == 0) ? 0.18033688011112042f : 1.0f;  // 0.125*log2(e)
      #pragma unroll
      for (int i = 0; i < 4; ++i){
        int n0 = nb + i*16 + lg*4;
        int hh = n0 >> 9, aa = n0 & 511;
        if (sec == 2){
          ushort4 pk;
          pk.x = f2b(acc[i][j][0] + bs);
          pk.y = f2b(acc[i][j][1] + bs);
          pk.z = f2b(acc[i][j][2] + bs);
          pk.w = f2b(acc[i][j][3] + bs);
          *reinterpret_cast<ushort4*>(vS + ((size_t)((hh<<3)+bb)*64 + dd)*512 + aa) = pk;
        } else {
          ushort* dst = (sec == 0) ? qS : kS;
          size_t base = ((size_t)((hh<<3)+bb)*512 + aa)*64 + dd;
          #pragma unroll
          for (int r = 0; r < 4; ++r)
            dst[base + (size_t)r*64] = f2b((acc[i][j][r] + bs) * qsc);
        }
      }
    }
  } else {
    #pragma unroll
    for (int j = 0; j < 4; ++j){
      int o = ob + j*16 + lr;
      float bs = bias[o];
      #pragma unroll
      for (int i = 0; i < 4; ++i){
        int n0 = nb + i*16 + lg*4;
        f32x4 xr = *reinterpret_cast<const f32x4*>(xres + (size_t)o*NSP + n0);
        f32x4 ov;
        #pragma unroll
        for (int r = 0; r < 4; ++r) ov[r] = acc[i][j][r] + bs + xr[r];
        *reinterpret_cast<f32x4*>(outF + (size_t)o*NSP + n0) = ov;
      }
    }
  }
}

// ---------- flash attention, swapped-QK 32x32 (m214-style) ----------
// Wave owns 32 q-rows. S^T = mfma32(K, Q): lane holds 16 scores of q = lane&31.
// Softmax fully in-register; P->A-frags via cvt_pk + permlane32_swap.
__global__ __launch_bounds__(256) void flash2(
    const ushort* __restrict__ qS, const ushort* __restrict__ kS,
    const ushort* __restrict__ vS, ushort* __restrict__ attnT)
{
  __shared__ __align__(16) float lbuf[4][32];
  int lane = threadIdx.x & 63, wv = threadIdx.x >> 6;
  int l31 = lane & 31, hi = lane >> 5;
  // bijective XCD swizzle: 256 blocks, 32/XCD -> each XCD handles one head
  int bx = (blockIdx.x & 7) * 32 + (blockIdx.x >> 3);
  int hh    = bx >> 5;
  int b1    = (bx >> 2) & 7;
  int chunk = bx & 3;
  int a0 = chunk * 128 + wv * 32;

  const ushort* qp = qS + ((size_t)((hh*8 + b1)*512) + a0 + l31)*64 + hi*8;
  s16x8 qf0 = ldfrag(qp), qf1 = ldfrag(qp+16), qf2 = ldfrag(qp+32), qf3 = ldfrag(qp+48);

  f32x16 O0 = {}, O1 = {};
  float mrun = -1e30f, lrun = 0.f;

  const ushort* kBase = kS + ((size_t)(hh*4096) + l31)*64 + hi*8;   // += t*2048
  // V: row = (hh*8 + (t>>4))*64 + dblk*32 + l31 ; col = (t&15)*32 + ks*16 + hi*8
  #define LOADK(T, F0, F1, F2, F3) { const ushort* kp = kBase + (size_t)(T)*2048; \
      F0 = ldfrag(kp); F1 = ldfrag(kp+16); F2 = ldfrag(kp+32); F3 = ldfrag(kp+48); }
  #define LOADV(T, F0, F1, F2, F3) { const ushort* vp = vS + ((size_t)((hh*8 + ((T)>>4))*64) + l31)*512 + ((T)&15)*32 + hi*8; \
      F0 = ldfrag(vp); F1 = ldfrag(vp+16); F2 = ldfrag(vp + 32*512); F3 = ldfrag(vp + 32*512 + 16); }

  s16x8 kA0,kA1,kA2,kA3, vA0,vA1,vA2,vA3;
  s16x8 kB0,kB1,kB2,kB3, vB0,vB1,vB2,vB3;
  LOADK(0, kA0,kA1,kA2,kA3);
  LOADV(0, vA0,vA1,vA2,vA3);

  #define COMPUTE(K0,K1,K2,K3, V0,V1,V2,V3) {                                  \
    f32x16 S = {};                                                             \
    S = mfma32(K0, qf0, S); S = mfma32(K1, qf1, S);                            \
    S = mfma32(K2, qf2, S); S = mfma32(K3, qf3, S);                            \
    float m8[8];                                                               \
    _Pragma("unroll") for (int i = 0; i < 8; ++i) m8[i] = fmaxf(S[2*i], S[2*i+1]); \
    float m4a = fmaxf(m8[0],m8[1]), m4b = fmaxf(m8[2],m8[3]);                  \
    float m4c = fmaxf(m8[4],m8[5]), m4d = fmaxf(m8[6],m8[7]);                  \
    float pm = fmaxf(fmaxf(m4a,m4b), fmaxf(m4c,m4d));                          \
    float su = pm, sv = pm;                                                    \
    asm("v_permlane32_swap_b32 %0, %1" : "+v"(su), "+v"(sv));                  \
    float pmax = fmaxf(su, sv);                                                \
    if (__any(pmax > mrun + 8.f)){                                             \
      float mnew  = fmaxf(mrun, pmax);                                         \
      float alpha = __builtin_amdgcn_exp2f(mrun - mnew);                       \
      lrun *= alpha;                                                           \
      if (hi == 0) lbuf[wv][l31] = alpha;                                      \
      asm volatile("s_waitcnt lgkmcnt(0)" ::: "memory");                       \
      _Pragma("unroll") for (int g = 0; g < 4; ++g){                           \
        f32x4 av = *reinterpret_cast<const f32x4*>(&lbuf[wv][g*8 + hi*4]);     \
        _Pragma("unroll") for (int r4 = 0; r4 < 4; ++r4){                      \
          O0[g*4+r4] *= av[r4]; O1[g*4+r4] *= av[r4]; }                        \
      }                                                                        \
      mrun = mnew;                                                             \
    }                                                                          \
    float p[16];                                                               \
    _Pragma("unroll") for (int r = 0; r < 16; ++r)                             \
      p[r] = __builtin_amdgcn_exp2f(S[r] - mrun);                              \
    float s8[8];                                                               \
    _Pragma("unroll") for (int i = 0; i < 8; ++i) s8[i] = p[2*i] + p[2*i+1];   \
    float s4a = s8[0]+s8[1], s4b = s8[2]+s8[3], s4c = s8[4]+s8[5], s4d = s8[6]+s8[7]; \
    float ts = (s4a+s4b) + (s4c+s4d);                                          \
    float tu = ts, tv = ts;                                                    \
    asm("v_permlane32_swap_b32 %0, %1" : "+v"(tu), "+v"(tv));                  \
    lrun += tu + tv;                                                           \
    unsigned A0 = cvtpk(p[0],p[1]),  A1 = cvtpk(p[2],p[3]);                    \
    unsigned B0 = cvtpk(p[4],p[5]),  B1 = cvtpk(p[6],p[7]);                    \
    asm("v_permlane32_swap_b32 %0, %1" : "+v"(A0), "+v"(B0));                  \
    asm("v_permlane32_swap_b32 %0, %1" : "+v"(A1), "+v"(B1));                  \
    unsigned C0 = cvtpk(p[8],p[9]),  C1 = cvtpk(p[10],p[11]);                  \
    unsigned D0 = cvtpk(p[12],p[13]),D1 = cvtpk(p[14],p[15]);                  \
    asm("v_permlane32_swap_b32 %0, %1" : "+v"(C0), "+v"(D0));                  \
    asm("v_permlane32_swap_b32 %0, %1" : "+v"(C1), "+v"(D1));                  \
    u32x4 w1 = {A0, A1, B0, B1}, w2 = {C0, C1, D0, D1};                        \
    s16x8 pa1 = __builtin_bit_cast(s16x8, w1);                                 \
    s16x8 pa2 = __builtin_bit_cast(s16x8, w2);                                 \
    O0 = mfma32(pa1, V0, O0); O0 = mfma32(pa2, V1, O0);                        \
    O1 = mfma32(pa1, V2, O1); O1 = mfma32(pa2, V3, O1);                        \
  }

  for (int t = 0; t < 128; t += 2){
    LOADK(t+1, kB0,kB1,kB2,kB3);
    LOADV(t+1, vB0,vB1,vB2,vB3);
    COMPUTE(kA0,kA1,kA2,kA3, vA0,vA1,vA2,vA3);
    if (t + 2 < 128){
      LOADK(t+2, kA0,kA1,kA2,kA3);
      LOADV(t+2, vA0,vA1,vA2,vA3);
    }
    COMPUTE(kB0,kB1,kB2,kB3, vB0,vB1,vB2,vB3);
  }

  // normalize + write: O rows are q, need lrun per q-row (broadcast via LDS)
  if (hi == 0) lbuf[wv][l31] = lrun;
  asm volatile("s_waitcnt lgkmcnt(0)" ::: "memory");
  size_t colBase = (size_t)b1*64 + l31;
  #pragma unroll
  for (int g = 0; g < 4; ++g){
    f32x4 lv = *reinterpret_cast<const f32x4*>(&lbuf[wv][g*8 + hi*4]);
    #pragma unroll
    for (int r4 = 0; r4 < 4; ++r4){
      float inv = 1.0f / lv[r4];
      int row = a0 + g*8 + hi*4 + r4;
      size_t base = ((size_t)(hh*512 + row))*CHN + colBase;
      attnT[base]      = f2b(O0[g*4+r4] * inv);
      attnT[base + 32] = f2b(O1[g*4+r4] * inv);
    }
  }
  #undef LOADK
  #undef LOADV
  #undef COMPUTE
}

extern "C" void kernel_launch(void* const* d_in, const int* in_sizes, int n_in,
                              void* d_out, int out_size, void* d_ws, size_t ws_size,
                              hipStream_t stream)
{
  (void)in_sizes; (void)n_in; (void)out_size; (void)ws_size;
  const float* x     = (const float*)d_in[0];
  const float* normw = (const float*)d_in[1];
  const float* normb = (const float*)d_in[2];
  const float* qkvw  = (const float*)d_in[3];
  const float* qkvb  = (const float*)d_in[4];
  const float* projw = (const float*)d_in[5];
  const float* projb = (const float*)d_in[6];
  float* out = (float*)d_out;

  char* w = (char*)d_ws;
  float*  stat = (float*)w;                                        // 1 KB
  ushort* h_t  = (ushort*)(w + 1024);                              // 4 MB (n,c) bf16 ; aliased as attnT
  ushort* Wq   = (ushort*)(w + 1024 + 4194304);                    // 1.5 MB
  ushort* Wp   = (ushort*)(w + 1024 + 4194304 + 1572864);          // 0.5 MB
  ushort* qSb  = (ushort*)(w + 1024 + 4194304 + 1572864 + 524288); // 4 MB
  ushort* kSb  = qSb + 2097152;                                    // 4 MB
  ushort* vSb  = kSb + 2097152;                                    // 4 MB
  ushort* attnT = h_t;

  cvt_bf16<<<768, 256, 0, stream>>>((const float4*)qkvw, (ushort4*)Wq, 196608);
  cvt_bf16<<<256, 256, 0, stream>>>((const float4*)projw, (ushort4*)Wp, 65536);
  gn_stats<<<32, 256, 0, stream>>>(x, stat);
  norm_apply<<<512, 256, 0, stream>>>(x, stat, normw, normb, h_t);
  gemm_tn<0><<<dim3(32, 12), 256, 0, stream>>>(h_t, Wq, qkvb, nullptr, qSb, kSb, vSb, nullptr);
  flash2<<<256, 256, 0, stream>>>(qSb, kSb, vSb, attnT);
  gemm_tn<1><<<dim3(32, 4), 256, 0, stream>>>(attnT, Wp, projb, x, nullptr, nullptr, nullptr, out);
}